// Round 7
// baseline (453.592 us; speedup 1.0000x reference)
//
#include <hip/hip_runtime.h>
#include <hip/hip_bf16.h>

typedef unsigned short u16;
typedef unsigned int u32;
typedef short bf16x8 __attribute__((ext_vector_type(8)));
typedef float f32x4 __attribute__((ext_vector_type(4)));

#define B_ 4
#define S_ 2048
#define E_ 1024
#define H_ 16
#define FF_ 4096
#define M_ 8192  // B*S

__device__ __forceinline__ u16 f2bf(float f) {
    u32 u = __float_as_uint(f);
    u32 r = (u + 0x7FFFu + ((u >> 16) & 1u)) >> 16;
    return (u16)r;
}
__device__ __forceinline__ u16 f2bf_h(float f) {
    __hip_bfloat16 h = __float2bfloat16(f);
    return *reinterpret_cast<u16*>(&h);
}
__device__ __forceinline__ float bf2f(u16 v) {
    return __uint_as_float(((u32)v) << 16);
}

__device__ __forceinline__ void gload16(const void* g, void* l) {
    __builtin_amdgcn_global_load_lds(
        (__attribute__((address_space(1))) void*)g,
        (__attribute__((address_space(3))) void*)l, 16, 0, 0);
}

// ---------------- fp32 -> bf16 cast (weights) ----------------
__global__ __launch_bounds__(256) void cvt_kernel(const float* __restrict__ in,
                                                  u16* __restrict__ out, int n4) {
    int i = blockIdx.x * 256 + threadIdx.x;
    if (i < n4) {
        float4 v = ((const float4*)in)[i];
        ushort4 o;
        o.x = f2bf(v.x); o.y = f2bf(v.y); o.z = f2bf(v.z); o.w = f2bf(v.w);
        ((ushort4*)out)[i] = o;
    }
}

// ---------------- LayerNorm (fp32 in -> bf16 out), one row per block ----------------
__global__ __launch_bounds__(256) void ln_kernel(const float* __restrict__ x,
                                                 const float* __restrict__ g,
                                                 const float* __restrict__ bb,
                                                 u16* __restrict__ out) {
    int row = blockIdx.x;
    int t = threadIdx.x;
    const float4* xr = (const float4*)(x + (size_t)row * E_);
    float4 v = xr[t];
    float s = v.x + v.y + v.z + v.w;
    float sq = v.x * v.x + v.y * v.y + v.z * v.z + v.w * v.w;
    for (int o = 1; o < 64; o <<= 1) {
        s += __shfl_xor(s, o, 64);
        sq += __shfl_xor(sq, o, 64);
    }
    __shared__ float ss[4], sqs[4];
    int w = t >> 6, l = t & 63;
    if (l == 0) { ss[w] = s; sqs[w] = sq; }
    __syncthreads();
    s = ss[0] + ss[1] + ss[2] + ss[3];
    sq = sqs[0] + sqs[1] + sqs[2] + sqs[3];
    float mean = s * (1.0f / E_);
    float var = sq * (1.0f / E_) - mean * mean;
    float rstd = rsqrtf(var + 1e-5f);
    float4 gv = ((const float4*)g)[t];
    float4 bv = ((const float4*)bb)[t];
    ushort4 o4;
    o4.x = f2bf((v.x - mean) * rstd * gv.x + bv.x);
    o4.y = f2bf((v.y - mean) * rstd * gv.y + bv.y);
    o4.z = f2bf((v.z - mean) * rstd * gv.z + bv.z);
    o4.w = f2bf((v.w - mean) * rstd * gv.w + bv.w);
    ((ushort4*)(out + (size_t)row * E_))[t] = o4;
}

// ---------------- GEMM BMx256, BK=64, 8 waves, 8-phase counted-vmcnt ----------------
// C[M,N] = A[M,K] @ Bt[N,K]^T + bias, bf16 in / fp32 acc. Waves 2m x 4n.
// BM=256: per-wave 128x64, vmcnt(6); BM=128: per-wave 64x64, vmcnt(5) (A stage = 1 gload).
// m-minor tile order: consecutive blocks in an XCD share one B panel (L2-resident).
// T2 swizzle: pre-swizzled gload SOURCE chunk, linear LDS dest, XOR on ds_read.
// EPI: 0 = bf16 store; 1 = fp32 store + residual; 2 = GELU -> bf16 store
template <int EPI, int BM>
__global__ __launch_bounds__(512, 2) void gemm256(const u16* __restrict__ A,
                                                  const u16* __restrict__ Bt,
                                                  const float* __restrict__ bias,
                                                  void* __restrict__ outp,
                                                  const float* __restrict__ resid,
                                                  int N, int K) {
    constexpr int AMI = BM / 64;       // A frags per quadrant read (4 or 2)
    constexpr int ABYTES = BM * 64;    // bytes per (buf,half) A region
    __shared__ u16 ldsA[2 * 2 * (BM * 32)];
    __shared__ u16 ldsB[2 * 2 * 8192];
    int t = threadIdx.x;
    int wid = t >> 6, l = t & 63, l15 = l & 15, hi4 = l >> 4;
    int wm = wid >> 2, wn = wid & 3;

    int nwg = gridDim.x;
    int flat = blockIdx.x;
    int swz = (flat & 7) * (nwg >> 3) + (flat >> 3);
    int nm = M_ / BM;  // m-minor: m-tile fastest within an XCD band
    int m0 = (swz % nm) * BM, n0 = (swz / nm) * 256;
    const size_t Kb = (size_t)K * 2;

    f32x4 acc[2 * AMI][4];
    f32x4 zf = {0.f, 0.f, 0.f, 0.f};
#pragma unroll
    for (int i = 0; i < 2 * AMI; i++)
#pragma unroll
        for (int j = 0; j < 4; j++) acc[i][j] = zf;

    auto stageA = [&](int buf, int h, int k0) {
#pragma unroll
        for (int rr = 0; rr < BM / 128; ++rr) {
            int o = t * 16 + rr * 8192;
            int lr = o >> 7;
            int gch = ((o >> 4) & 7) ^ (lr & 7);
            int grow = m0 + (lr / (BM / 4)) * (BM / 2) + h * (BM / 4) + (lr % (BM / 4));
            gload16((const char*)A + (size_t)grow * Kb + k0 * 2 + gch * 16,
                    (char*)ldsA + (buf * 2 + h) * ABYTES + o);
        }
    };
    auto stageB = [&](int buf, int h, int k0) {
#pragma unroll
        for (int rr = 0; rr < 2; ++rr) {
            int o = t * 16 + rr * 8192;
            int lr = o >> 7;
            int gch = ((o >> 4) & 7) ^ (lr & 7);
            int grow = n0 + (lr >> 5) * 64 + h * 32 + (lr & 31);
            gload16((const char*)Bt + (size_t)grow * Kb + k0 * 2 + gch * 16,
                    (char*)ldsB + (buf * 2 + h) * 16384 + o);
        }
    };

    auto readA = [&](int bq, int mh, bf16x8 (&af)[AMI][2]) {
#pragma unroll
        for (int mi = 0; mi < AMI; mi++)
#pragma unroll
            for (int ks = 0; ks < 2; ks++) {
                int lr = wm * (BM / 4) + mi * 16 + l15;
                int ob = lr * 128 + ks * 64 + hi4 * 16;
                af[mi][ks] = *(const bf16x8*)((const char*)ldsA +
                             (bq * 2 + mh) * ABYTES + (ob ^ ((lr & 7) << 4)));
            }
    };
    auto readB = [&](int bq, int nh, bf16x8 (&bfr)[2][2]) {
#pragma unroll
        for (int nq = 0; nq < 2; nq++)
#pragma unroll
            for (int ks = 0; ks < 2; ks++) {
                int lr = wn * 32 + nq * 16 + l15;
                int ob = lr * 128 + ks * 64 + hi4 * 16;
                bfr[nq][ks] = *(const bf16x8*)((const char*)ldsB +
                              (bq * 2 + nh) * 16384 + (ob ^ ((lr & 7) << 4)));
            }
    };
    auto mma = [&](bf16x8 (&af)[AMI][2], bf16x8 (&bfr)[2][2], int mh, int nh) {
#pragma unroll
        for (int mi = 0; mi < AMI; mi++)
#pragma unroll
            for (int nq = 0; nq < 2; nq++)
#pragma unroll
                for (int ks = 0; ks < 2; ks++)
                    acc[mh * AMI + mi][nh * 2 + nq] =
                        __builtin_amdgcn_mfma_f32_16x16x32_bf16(
                            af[mi][ks], bfr[nq][ks], acc[mh * AMI + mi][nh * 2 + nq], 0, 0, 0);
    };

#define WAITN                                                          \
    do {                                                               \
        if constexpr (BM == 256) {                                     \
            asm volatile("s_waitcnt vmcnt(6)" ::: "memory");           \
        } else {                                                       \
            asm volatile("s_waitcnt vmcnt(5)" ::: "memory");           \
        }                                                              \
        __builtin_amdgcn_sched_barrier(0);                             \
    } while (0)
#define PH_MID                                              \
    __builtin_amdgcn_s_barrier();                           \
    asm volatile("s_waitcnt lgkmcnt(0)" ::: "memory");      \
    __builtin_amdgcn_sched_barrier(0);                      \
    __builtin_amdgcn_s_setprio(1);
#define PH_END                                              \
    __builtin_amdgcn_s_setprio(0);                          \
    __builtin_amdgcn_s_barrier();

    int KT = K >> 6, ITERS = KT >> 1;

    // prologue: tile0 full (buf0), tile1 B0,B1,A0 (buf1)
    stageB(0, 0, 0); stageB(0, 1, 0); stageA(0, 0, 0); stageA(0, 1, 0);
    stageB(1, 0, 64); stageB(1, 1, 64); stageA(1, 0, 64);
    WAITN;
    __builtin_amdgcn_s_barrier();
    for (int s = 0; s < ITERS; ++s) {
        int k1 = (2 * s + 1) << 6;
        int k2 = (2 * s + 2) << 6; if (k2 >= K) k2 = 0;
        int k3 = (2 * s + 3) << 6; if (k3 >= K) k3 = 0;
        bf16x8 af[AMI][2], b0[2][2], b1[2][2];
        readA(0, 0, af); readB(0, 0, b0); stageA(1, 1, k1);
        PH_MID; mma(af, b0, 0, 0); PH_END;
        readB(0, 1, b1); stageB(0, 0, k2);
        PH_MID; mma(af, b1, 0, 1); PH_END;
        readA(0, 1, af); stageB(0, 1, k2);
        PH_MID; mma(af, b0, 1, 0); PH_END;
        stageA(0, 0, k2); WAITN;
        PH_MID; mma(af, b1, 1, 1); PH_END;
        readA(1, 0, af); readB(1, 0, b0); stageA(0, 1, k2);
        PH_MID; mma(af, b0, 0, 0); PH_END;
        readB(1, 1, b1); stageB(1, 0, k3);
        PH_MID; mma(af, b1, 0, 1); PH_END;
        readA(1, 1, af); stageB(1, 1, k3);
        PH_MID; mma(af, b0, 1, 0); PH_END;
        stageA(1, 0, k3); WAITN;
        PH_MID; mma(af, b1, 1, 1); PH_END;
    }
#undef WAITN
#undef PH_MID
#undef PH_END

    float bias_v[4];
#pragma unroll
    for (int nf = 0; nf < 4; nf++) bias_v[nf] = bias[n0 + wn * 64 + nf * 16 + l15];

#pragma unroll
    for (int mf = 0; mf < 2 * AMI; mf++)
#pragma unroll
        for (int nf = 0; nf < 4; nf++)
#pragma unroll
            for (int j = 0; j < 4; j++) {
                int row = m0 + wm * (BM / 2) + mf * 16 + hi4 * 4 + j;
                int col = n0 + wn * 64 + nf * 16 + l15;
                float v = acc[mf][nf][j] + bias_v[nf];
                size_t idx = (size_t)row * N + col;
                if (EPI == 2) v = 0.5f * v * (1.0f + erff(v * 0.70710678118f));
                if (EPI == 1)
                    ((float*)outp)[idx] = resid[idx] + v;
                else
                    ((u16*)outp)[idx] = f2bf(v);
            }
}

// ---------------- Flash attention, 16 Q-rows per wave (folded causal grid) ----------------
// 1024 blocks = 64 bh x 16 pairs; 4 waves x 16 rows; qt=p and qt=31-p sequentially.
// 4 blocks/CU. Periodic mask hoisted ((col%32)==31 <=> nf odd && c==15); causal compare
// skipped on wave-uniformly full tiles. exp2 softmax, ones-MFMA denominator, defer-max.
__global__ __launch_bounds__(256) void attn_kernel(const u16* __restrict__ qkv,
                                                   u16* __restrict__ aout) {
    __shared__ u16 Ks[64 * 64];
    __shared__ u16 Vt[64 * 64];
    __shared__ u16 Ps[4][16 * 64];
    int t = threadIdx.x, wv = t >> 6, l = t & 63, c = l & 15, gq = l >> 4;
    int flat = blockIdx.x;
    int logical = (flat & 7) * 128 + (flat >> 3);
    int bh = logical >> 4, p0 = logical & 15;
    int b = bh >> 4, h = bh & 15;

    const float qscale = 0.18033688011f;  // log2(e)/sqrt(64)
    bool cbq = (c == 15);                 // periodic mask hits only cols 16nf+15, nf odd
    bf16x8 onesf;
#pragma unroll
    for (int e = 0; e < 8; e++) onesf[e] = (short)0x3F80;

    for (int half = 0; half < 2; ++half) {
        int qt = half ? (31 - p0) : p0;
        int i0 = qt * 64;
        int i0w = i0 + 16 * wv;

        bf16x8 qf[2];
#pragma unroll
        for (int ks = 0; ks < 2; ks++) {
            const u16* src = qkv + (size_t)(b * S_ + i0w + c) * 3072 + h * 64 + 32 * ks + 8 * gq;
            uint4 d16 = *(const uint4*)src;
            u32 uu[4] = {d16.x, d16.y, d16.z, d16.w};
#pragma unroll
            for (int e = 0; e < 8; e++) {
                u16 raw = (e & 1) ? (u16)(uu[e >> 1] >> 16) : (u16)(uu[e >> 1] & 0xffffu);
                qf[ks][e] = (short)f2bf(bf2f(raw) * qscale);
            }
        }

        f32x4 Ol;
        f32x4 zf = {0.f, 0.f, 0.f, 0.f};
        float mrun[4];
        Ol = zf;
        f32x4 Od[4];
#pragma unroll
        for (int j = 0; j < 4; j++) mrun[j] = -INFINITY;
#pragma unroll
        for (int nd = 0; nd < 4; nd++) Od[nd] = zf;

        int ntiles = qt + 1;
        for (int jt = 0; jt < ntiles; ++jt) {
            int j0 = jt * 64;
            __syncthreads();
#pragma unroll
            for (int pp = 0; pp < 2; pp++) {
                int oo = 16 * t + 4096 * pp;
                int row = oo >> 7, colb = oo & 127;
                const u16* src = qkv + E_ + (size_t)(b * S_ + j0 + row) * 3072 + h * 64 + (colb >> 1);
                uint4 d16 = *(const uint4*)src;
                int el = (((row << 6) + (colb >> 1)) ^ ((row & 7) << 3));
                *(uint4*)&Ks[el] = d16;
            }
#pragma unroll
            for (int pp = 0; pp < 2; pp++) {
                int db = wv + 4 * pp;
                const u16* src = qkv + 2 * E_ + (size_t)(b * S_ + j0 + l) * 3072 + h * 64 + db * 8;
                uint4 d16 = *(const uint4*)src;
                u32 uu[4] = {d16.x, d16.y, d16.z, d16.w};
#pragma unroll
                for (int e = 0; e < 8; e++) {
                    u16 raw = (e & 1) ? (u16)(uu[e >> 1] >> 16) : (u16)(uu[e >> 1] & 0xffffu);
                    int d = db * 8 + e;
                    Vt[((d << 6) + l) ^ ((d & 7) << 3)] = raw;
                }
            }
            __syncthreads();

            f32x4 sf[4];
            __builtin_amdgcn_s_setprio(1);
#pragma unroll
            for (int nf = 0; nf < 4; nf++) {
                sf[nf] = zf;
#pragma unroll
                for (int ks = 0; ks < 2; ks++) {
                    int kr = 16 * nf + c;
                    bf16x8 kf = *(const bf16x8*)&Ks[((kr << 6) + 32 * ks + 8 * gq) ^ ((kr & 7) << 3)];
                    sf[nf] = __builtin_amdgcn_mfma_f32_16x16x32_bf16(qf[ks], kf, sf[nf], 0, 0, 0);
                }
            }
            __builtin_amdgcn_s_setprio(0);

            // mask + row max
            float rmx[4];
            bool keep = true;
            bool notfull = (j0 + 64 > i0w);  // wave-uniform causal-boundary flag
#pragma unroll
            for (int j = 0; j < 4; j++) {
                int row = i0w + 4 * gq + j;
                float mx = -INFINITY;
                if (notfull) {
#pragma unroll
                    for (int nf = 0; nf < 4; nf++) {
                        int col = j0 + 16 * nf + c;
                        float v = sf[nf][j];
                        bool bad = (col > row) || ((nf & 1) && cbq);
                        v = bad ? -INFINITY : v;
                        sf[nf][j] = v;
                        mx = fmaxf(mx, v);
                    }
                } else {
#pragma unroll
                    for (int nf = 0; nf < 4; nf++) {
                        float v = sf[nf][j];
                        if (nf & 1) {
                            v = cbq ? -INFINITY : v;
                            sf[nf][j] = v;
                        }
                        mx = fmaxf(mx, v);
                    }
                }
                mx = fmaxf(mx, __shfl_xor(mx, 1, 64));
                mx = fmaxf(mx, __shfl_xor(mx, 2, 64));
                mx = fmaxf(mx, __shfl_xor(mx, 4, 64));
                mx = fmaxf(mx, __shfl_xor(mx, 8, 64));
                rmx[j] = mx;
                keep = keep && (mx <= mrun[j] + 8.0f);  // false while mrun=-inf
            }
            bool dokeep = __all(keep);

#pragma unroll
            for (int j = 0; j < 4; j++) {
                float mnew = mrun[j];
                if (!dokeep) {
                    float mold = mnew;
                    mnew = fmaxf(mold, rmx[j]);
                    float sc = __builtin_amdgcn_exp2f(mold - mnew);
                    mrun[j] = mnew;
#pragma unroll
                    for (int nd = 0; nd < 4; nd++) Od[nd][j] *= sc;
                    Ol[j] *= sc;
                }
#pragma unroll
                for (int nf = 0; nf < 4; nf++)
                    sf[nf][j] = __builtin_amdgcn_exp2f(sf[nf][j] - mnew);
            }

#pragma unroll
            for (int nf = 0; nf < 4; nf++)
#pragma unroll
                for (int j = 0; j < 4; j++) {
                    int pr = 4 * gq + j;
                    Ps[wv][((pr << 6) + 16 * nf + c) ^ ((pr & 7) << 3)] = f2bf_h(sf[nf][j]);
                }
            asm volatile("s_waitcnt lgkmcnt(0)" ::: "memory");
            __builtin_amdgcn_sched_barrier(0);

            bf16x8 pf[2], vfr[2][4];
#pragma unroll
            for (int ks = 0; ks < 2; ks++) {
                int pr = c;
                pf[ks] = *(const bf16x8*)&Ps[wv][((pr << 6) + 32 * ks + 8 * gq) ^ ((pr & 7) << 3)];
            }
#pragma unroll
            for (int ks = 0; ks < 2; ks++)
#pragma unroll
                for (int nd = 0; nd < 4; nd++) {
                    int d = 16 * nd + c;
                    vfr[ks][nd] = *(const bf16x8*)&Vt[((d << 6) + 32 * ks + 8 * gq) ^ ((d & 7) << 3)];
                }
            __builtin_amdgcn_s_setprio(1);
#pragma unroll
            for (int nd = 0; nd < 4; nd++)
#pragma unroll
                for (int ks = 0; ks < 2; ks++)
                    Od[nd] = __builtin_amdgcn_mfma_f32_16x16x32_bf16(pf[ks], vfr[ks][nd], Od[nd], 0, 0, 0);
#pragma unroll
            for (int ks = 0; ks < 2; ks++)
                Ol = __builtin_amdgcn_mfma_f32_16x16x32_bf16(pf[ks], onesf, Ol, 0, 0, 0);
            __builtin_amdgcn_s_setprio(0);
        }

#pragma unroll
        for (int j = 0; j < 4; j++) {
            float inv = 1.0f / Ol[j];
            int row = i0w + 4 * gq + j;
#pragma unroll
            for (int nd = 0; nd < 4; nd++) {
                int d = 16 * nd + c;
                aout[(size_t)(b * S_ + row) * E_ + h * 64 + d] = f2bf(Od[nd][j] * inv);
            }
        }
    }
}

extern "C" void kernel_launch(void* const* d_in, const int* in_sizes, int n_in,
                              void* d_out, int out_size, void* d_ws, size_t ws_size,
                              hipStream_t stream) {
    const float* x = (const float*)d_in[0];
    const float* ln1_g = (const float*)d_in[2];
    const float* ln1_b = (const float*)d_in[3];
    const float* ln2_g = (const float*)d_in[4];
    const float* ln2_b = (const float*)d_in[5];
    const float* w_qkv = (const float*)d_in[6];
    const float* b_qkv = (const float*)d_in[7];
    const float* w_o = (const float*)d_in[8];
    const float* b_o = (const float*)d_in[9];
    const float* w_fc1 = (const float*)d_in[10];
    const float* b_fc1 = (const float*)d_in[11];
    const float* w_fc2 = (const float*)d_in[12];
    const float* b_fc2 = (const float*)d_in[13];
    float* out = (float*)d_out;
    char* ws = (char*)d_ws;

    u16* wqkv_bf = (u16*)(ws);                  // 6291456
    u16* wo_bf   = (u16*)(ws + 6291456);        // 2097152
    u16* wfc1_bf = (u16*)(ws + 8388608);        // 8388608
    u16* wfc2_bf = (u16*)(ws + 16777216);       // 8388608
    u16* xn_bf   = (u16*)(ws + 25165824);       // 16777216 (LN1 out; reused as LN2 out)
    u16* qkv_bf  = (u16*)(ws + 41943040);       // 50331648 (reused by ffn1)
    u16* ffn1_bf = (u16*)(ws + 41943040);       // 67108864
    u16* attn_bf = (u16*)(ws + 92274688);       // 16777216
    float* x2    = (float*)(ws + 109051904);    // 33554432
    (void)in_sizes; (void)n_in; (void)out_size; (void)ws_size;

    cvt_kernel<<<3072, 256, 0, stream>>>(w_qkv, wqkv_bf, 786432);
    cvt_kernel<<<1024, 256, 0, stream>>>(w_o, wo_bf, 262144);
    cvt_kernel<<<4096, 256, 0, stream>>>(w_fc1, wfc1_bf, 1048576);
    cvt_kernel<<<4096, 256, 0, stream>>>(w_fc2, wfc2_bf, 1048576);

    ln_kernel<<<M_, 256, 0, stream>>>(x, ln1_g, ln1_b, xn_bf);

    // qkv: 64 m x 12 n = 768 blocks = 3 full rounds
    gemm256<0, 128><<<768, 512, 0, stream>>>(xn_bf, wqkv_bf, b_qkv, qkv_bf, nullptr, 3072, 1024);

    attn_kernel<<<1024, 256, 0, stream>>>(qkv_bf, attn_bf);

    // w_o: 64 m x 4 n = 256 blocks = 1 full round
    gemm256<1, 128><<<256, 512, 0, stream>>>(attn_bf, wo_bf, b_o, x2, x, 1024, 1024);

    ln_kernel<<<M_, 256, 0, stream>>>(x2, ln2_g, ln2_b, xn_bf);

    // fc1: 32 m x 16 n = 512 blocks = 2 full rounds (BM=256, best intensity)
    gemm256<2, 256><<<512, 512, 0, stream>>>(xn_bf, wfc1_bf, b_fc1, ffn1_bf, nullptr, 4096, 1024);

    // fc2: 64 m x 4 n = 256 blocks = 1 full round
    gemm256<1, 128><<<256, 512, 0, stream>>>(ffn1_bf, wfc2_bf, b_fc2, out, x2, 1024, 4096);
}

// Round 8
// 404.643 us; speedup vs baseline: 1.1210x; 1.1210x over previous
//
#include <hip/hip_runtime.h>
#include <hip/hip_bf16.h>

typedef unsigned short u16;
typedef unsigned int u32;
typedef short bf16x8 __attribute__((ext_vector_type(8)));
typedef float f32x4 __attribute__((ext_vector_type(4)));
typedef float f32x16 __attribute__((ext_vector_type(16)));

#define B_ 4
#define S_ 2048
#define E_ 1024
#define H_ 16
#define FF_ 4096
#define M_ 8192  // B*S

__device__ __forceinline__ u16 f2bf(float f) {
    u32 u = __float_as_uint(f);
    u32 r = (u + 0x7FFFu + ((u >> 16) & 1u)) >> 16;
    return (u16)r;
}
__device__ __forceinline__ float bf2f(u16 v) {
    return __uint_as_float(((u32)v) << 16);
}
__device__ __forceinline__ u32 cvtpk(float lo, float hi) {
    u32 r;
    asm("v_cvt_pk_bf16_f32 %0, %1, %2" : "=v"(r) : "v"(lo), "v"(hi));
    return r;
}
__device__ __forceinline__ void pswap(u32& a, u32& b) {
    asm("v_permlane32_swap_b32 %0, %1" : "+v"(a), "+v"(b));
}

__device__ __forceinline__ void gload16(const void* g, void* l) {
    __builtin_amdgcn_global_load_lds(
        (__attribute__((address_space(1))) void*)g,
        (__attribute__((address_space(3))) void*)l, 16, 0, 0);
}

// ---------------- fp32 -> bf16 cast (weights) ----------------
__global__ __launch_bounds__(256) void cvt_kernel(const float* __restrict__ in,
                                                  u16* __restrict__ out, int n4) {
    int i = blockIdx.x * 256 + threadIdx.x;
    if (i < n4) {
        float4 v = ((const float4*)in)[i];
        ushort4 o;
        o.x = f2bf(v.x); o.y = f2bf(v.y); o.z = f2bf(v.z); o.w = f2bf(v.w);
        ((ushort4*)out)[i] = o;
    }
}

// ---------------- LayerNorm (fp32 in -> bf16 out), one row per block ----------------
__global__ __launch_bounds__(256) void ln_kernel(const float* __restrict__ x,
                                                 const float* __restrict__ g,
                                                 const float* __restrict__ bb,
                                                 u16* __restrict__ out) {
    int row = blockIdx.x;
    int t = threadIdx.x;
    const float4* xr = (const float4*)(x + (size_t)row * E_);
    float4 v = xr[t];
    float s = v.x + v.y + v.z + v.w;
    float sq = v.x * v.x + v.y * v.y + v.z * v.z + v.w * v.w;
    for (int o = 1; o < 64; o <<= 1) {
        s += __shfl_xor(s, o, 64);
        sq += __shfl_xor(sq, o, 64);
    }
    __shared__ float ss[4], sqs[4];
    int w = t >> 6, l = t & 63;
    if (l == 0) { ss[w] = s; sqs[w] = sq; }
    __syncthreads();
    s = ss[0] + ss[1] + ss[2] + ss[3];
    sq = sqs[0] + sqs[1] + sqs[2] + sqs[3];
    float mean = s * (1.0f / E_);
    float var = sq * (1.0f / E_) - mean * mean;
    float rstd = rsqrtf(var + 1e-5f);
    float4 gv = ((const float4*)g)[t];
    float4 bv = ((const float4*)bb)[t];
    ushort4 o4;
    o4.x = f2bf((v.x - mean) * rstd * gv.x + bv.x);
    o4.y = f2bf((v.y - mean) * rstd * gv.y + bv.y);
    o4.z = f2bf((v.z - mean) * rstd * gv.z + bv.z);
    o4.w = f2bf((v.w - mean) * rstd * gv.w + bv.w);
    ((ushort4*)(out + (size_t)row * E_))[t] = o4;
}

// ---------------- GEMM 256xBN, BK=64, 8 waves, phase-interleaved counted-vmcnt ----------
// Round-6 version (best GEMM measured). Fragment-reuse: B frags live in regs across the
// K-tile, A-quadrant across 2 phases. BN=256: 8 phases/iter, vmcnt(6) at P4/P8.
// BN=128: 4 phases/iter, vmcnt(4). n-minor tile order.
// EPI: 0 = bf16 store; 1 = fp32 store + residual; 2 = GELU -> bf16 store
template <int EPI, int BN>
__global__ __launch_bounds__(512, 2) void gemm256(const u16* __restrict__ A,
                                                  const u16* __restrict__ Bt,
                                                  const float* __restrict__ bias,
                                                  void* __restrict__ outp,
                                                  const float* __restrict__ resid,
                                                  int N, int K) {
    constexpr int NF = BN / 64;
    __shared__ u16 ldsA[2 * 2 * 8192];
    __shared__ u16 ldsB[BN == 256 ? 2 * 2 * 8192 : 2 * 8192];
    int t = threadIdx.x;
    int wid = t >> 6, l = t & 63, l15 = l & 15, hi4 = l >> 4;
    int wm = wid >> 2, wn = wid & 3;

    int nwg = gridDim.x;
    int flat = blockIdx.x;
    int swz = (flat & 7) * (nwg >> 3) + (flat >> 3);
    int nx = N / BN;
    int m0 = (swz / nx) * 256, n0 = (swz % nx) * BN;
    const size_t Kb = (size_t)K * 2;

    f32x4 acc[8][NF];
    f32x4 zf = {0.f, 0.f, 0.f, 0.f};
#pragma unroll
    for (int i = 0; i < 8; i++)
#pragma unroll
        for (int j = 0; j < NF; j++) acc[i][j] = zf;

    auto stageA = [&](int buf, int h, int k0) {
#pragma unroll
        for (int rr = 0; rr < 2; ++rr) {
            int o = t * 16 + rr * 8192;
            int lr = o >> 7;
            int gch = ((o >> 4) & 7) ^ (lr & 7);
            int grow = m0 + (lr >> 6) * 128 + h * 64 + (lr & 63);
            gload16((const char*)A + (size_t)grow * Kb + k0 * 2 + gch * 16,
                    (char*)ldsA + (buf * 2 + h) * 16384 + o);
        }
    };
    auto stageB256 = [&](int buf, int h, int k0) {
#pragma unroll
        for (int rr = 0; rr < 2; ++rr) {
            int o = t * 16 + rr * 8192;
            int lr = o >> 7;
            int gch = ((o >> 4) & 7) ^ (lr & 7);
            int grow = n0 + (lr >> 5) * 64 + h * 32 + (lr & 31);
            gload16((const char*)Bt + (size_t)grow * Kb + k0 * 2 + gch * 16,
                    (char*)ldsB + (buf * 2 + h) * 16384 + o);
        }
    };
    auto stageB128 = [&](int buf, int k0) {
#pragma unroll
        for (int rr = 0; rr < 2; ++rr) {
            int o = t * 16 + rr * 8192;
            int lr = o >> 7;
            int gch = ((o >> 4) & 7) ^ (lr & 7);
            int grow = n0 + lr;
            gload16((const char*)Bt + (size_t)grow * Kb + k0 * 2 + gch * 16,
                    (char*)ldsB + buf * 16384 + o);
        }
    };

    auto readA = [&](int bq, int mh, bf16x8 (&af)[4][2]) {
#pragma unroll
        for (int mi = 0; mi < 4; mi++)
#pragma unroll
            for (int ks = 0; ks < 2; ks++) {
                int lr = wm * 64 + mi * 16 + l15;
                int ob = lr * 128 + ks * 64 + hi4 * 16;
                af[mi][ks] = *(const bf16x8*)((const char*)ldsA +
                             (bq * 2 + mh) * 16384 + (ob ^ ((lr & 7) << 4)));
            }
    };
    auto readB256 = [&](int bq, int nh, bf16x8 (&bfr)[2][2]) {
#pragma unroll
        for (int nq = 0; nq < 2; nq++)
#pragma unroll
            for (int ks = 0; ks < 2; ks++) {
                int lr = wn * 32 + nq * 16 + l15;
                int ob = lr * 128 + ks * 64 + hi4 * 16;
                bfr[nq][ks] = *(const bf16x8*)((const char*)ldsB +
                              (bq * 2 + nh) * 16384 + (ob ^ ((lr & 7) << 4)));
            }
    };
    auto readB128 = [&](int bq, bf16x8 (&bfr)[2][2]) {
#pragma unroll
        for (int nq = 0; nq < 2; nq++)
#pragma unroll
            for (int ks = 0; ks < 2; ks++) {
                int lr = wn * 32 + nq * 16 + l15;
                int ob = lr * 128 + ks * 64 + hi4 * 16;
                bfr[nq][ks] = *(const bf16x8*)((const char*)ldsB +
                              bq * 16384 + (ob ^ ((lr & 7) << 4)));
            }
    };
    auto mma = [&](bf16x8 (&af)[4][2], bf16x8 (&bfr)[2][2], int mh, int nh) {
#pragma unroll
        for (int mi = 0; mi < 4; mi++)
#pragma unroll
            for (int nq = 0; nq < 2; nq++)
#pragma unroll
                for (int ks = 0; ks < 2; ks++)
                    acc[mh * 4 + mi][nh * 2 + nq] =
                        __builtin_amdgcn_mfma_f32_16x16x32_bf16(
                            af[mi][ks], bfr[nq][ks], acc[mh * 4 + mi][nh * 2 + nq], 0, 0, 0);
    };

#define GWAIT(N)                                            \
    asm volatile("s_waitcnt vmcnt(" #N ")" ::: "memory");   \
    __builtin_amdgcn_sched_barrier(0);
#define PH_MID                                              \
    __builtin_amdgcn_s_barrier();                           \
    asm volatile("s_waitcnt lgkmcnt(0)" ::: "memory");      \
    __builtin_amdgcn_sched_barrier(0);                      \
    __builtin_amdgcn_s_setprio(1);
#define PH_END                                              \
    __builtin_amdgcn_s_setprio(0);                          \
    __builtin_amdgcn_s_barrier();

    int KT = K >> 6, ITERS = KT >> 1;

    if constexpr (BN == 256) {
        stageB256(0, 0, 0); stageB256(0, 1, 0); stageA(0, 0, 0); stageA(0, 1, 0);
        stageB256(1, 0, 64); stageB256(1, 1, 64); stageA(1, 0, 64);
        GWAIT(6);
        __builtin_amdgcn_s_barrier();
        for (int s = 0; s < ITERS; ++s) {
            int k1 = (2 * s + 1) << 6;
            int k2 = (2 * s + 2) << 6; if (k2 >= K) k2 = 0;
            int k3 = (2 * s + 3) << 6; if (k3 >= K) k3 = 0;
            bf16x8 af[4][2], b0[2][2], b1[2][2];
            readA(0, 0, af); readB256(0, 0, b0); stageA(1, 1, k1);
            PH_MID; mma(af, b0, 0, 0); PH_END;
            readB256(0, 1, b1); stageB256(0, 0, k2);
            PH_MID; mma(af, b1, 0, 1); PH_END;
            readA(0, 1, af); stageB256(0, 1, k2);
            PH_MID; mma(af, b0, 1, 0); PH_END;
            stageA(0, 0, k2); GWAIT(6);
            PH_MID; mma(af, b1, 1, 1); PH_END;
            readA(1, 0, af); readB256(1, 0, b0); stageA(0, 1, k2);
            PH_MID; mma(af, b0, 0, 0); PH_END;
            readB256(1, 1, b1); stageB256(1, 0, k3);
            PH_MID; mma(af, b1, 0, 1); PH_END;
            readA(1, 1, af); stageB256(1, 1, k3);
            PH_MID; mma(af, b0, 1, 0); PH_END;
            stageA(1, 0, k3); GWAIT(6);
            PH_MID; mma(af, b1, 1, 1); PH_END;
        }
    } else {
        stageB128(0, 0); stageA(0, 0, 0); stageA(0, 1, 0);
        stageB128(1, 64); stageA(1, 0, 64);
        GWAIT(4);
        __builtin_amdgcn_s_barrier();
        for (int s = 0; s < ITERS; ++s) {
            int k1 = (2 * s + 1) << 6;
            int k2 = (2 * s + 2) << 6; if (k2 >= K) k2 = 0;
            int k3 = (2 * s + 3) << 6; if (k3 >= K) k3 = 0;
            bf16x8 af[4][2], br[2][2];
            readA(0, 0, af); readB128(0, br); stageA(1, 1, k1);
            PH_MID; mma(af, br, 0, 0); PH_END;
            readA(0, 1, af); stageB128(0, k2); stageA(0, 0, k2); GWAIT(4);
            PH_MID; mma(af, br, 1, 0); PH_END;
            readA(1, 0, af); readB128(1, br); stageA(0, 1, k2);
            PH_MID; mma(af, br, 0, 0); PH_END;
            readA(1, 1, af); stageB128(1, k3); stageA(1, 0, k3); GWAIT(4);
            PH_MID; mma(af, br, 1, 0); PH_END;
        }
    }
#undef GWAIT
#undef PH_MID
#undef PH_END

    float bias_v[NF];
#pragma unroll
    for (int nf = 0; nf < NF; nf++) bias_v[nf] = bias[n0 + wn * (NF * 16) + nf * 16 + l15];

#pragma unroll
    for (int mf = 0; mf < 8; mf++)
#pragma unroll
        for (int nf = 0; nf < NF; nf++)
#pragma unroll
            for (int j = 0; j < 4; j++) {
                int row = m0 + wm * 128 + mf * 16 + hi4 * 4 + j;
                int col = n0 + wn * (NF * 16) + nf * 16 + l15;
                float v = acc[mf][nf][j] + bias_v[nf];
                size_t idx = (size_t)row * N + col;
                if (EPI == 2) v = 0.5f * v * (1.0f + erff(v * 0.70710678118f));
                if (EPI == 1)
                    ((float*)outp)[idx] = resid[idx] + v;
                else
                    ((u16*)outp)[idx] = f2bf(v);
            }
}

// ---------------- Flash attention: swapped QK^T, lane-local rows (T12) ----------------
// 2048 blocks x 128 thr (2 waves x 32 Q rows). Block = (bh, qt), qt heavy-first.
// S^T = mfma_32x32x16(K, Q): lane q = lane&31 owns its full row; in-register softmax
// (exp2-domain, scale folded into exp), defer-max, cvt_pk+permlane32_swap P->bf16,
// O^T = mfma(V^T, P^T) keeps O lane-home = q (rescale/normalize lane-local).
// Periodic mask = reg15/hi only; causal compare only on the one boundary tile (jt==qt).
__global__ __launch_bounds__(128) void attn_kernel(const u16* __restrict__ qkv,
                                                   u16* __restrict__ aout) {
    __shared__ u16 Ks[64 * 64];
    __shared__ u16 Vt[64 * 64];
    int t = threadIdx.x;
    int wv = t >> 6, l = t & 63;
    int q31 = l & 31, hi = l >> 5;
    int flat = blockIdx.x;
    int logical = (flat & 7) * 256 + (flat >> 3);  // XCD x owns bh [8x, 8x+8)
    int bh = logical >> 5;
    int qt = 31 - (logical & 31);                  // heavy blocks dispatch first
    int b = bh >> 4, h = bh & 15;
    int rowq = qt * 64 + wv * 32 + q31;

    const float qs = 0.18033688011f;   // log2(e)/sqrt(64)
    const float THR = 44.3616f;        // 8 / qs (defer-max threshold, raw domain)

    // Q fragments (raw bf16; scale folded into exp)
    bf16x8 qreg[4];
    const u16* qbase = qkv + (size_t)(b * S_ + rowq) * 3072 + h * 64 + hi * 8;
#pragma unroll
    for (int g = 0; g < 4; g++) qreg[g] = *(const bf16x8*)(qbase + 16 * g);

    f32x16 zf16;
#pragma unroll
    for (int r = 0; r < 16; r++) zf16[r] = 0.f;
    f32x16 o0 = zf16, o1 = zf16;
    float mrun = -INFINITY, lrun = 0.f;

    for (int jt = 0; jt <= qt; ++jt) {
        int j0 = jt * 64;
        __syncthreads();
        // stage K [64 kv x 64 d], row-XOR swizzled
#pragma unroll
        for (int pp = 0; pp < 4; pp++) {
            int oo = 16 * t + 2048 * pp;
            int row = oo >> 7, colb = oo & 127;
            const u16* src = qkv + E_ + (size_t)(b * S_ + j0 + row) * 3072 + h * 64 + (colb >> 1);
            uint4 d16 = *(const uint4*)src;
            int el = (((row << 6) + (colb >> 1)) ^ ((row & 7) << 3));
            *(uint4*)&Ks[el] = d16;
        }
        // stage V transposed Vt[d][kv], row-XOR swizzled
#pragma unroll
        for (int pp = 0; pp < 4; pp++) {
            int db = wv + 2 * pp;
            const u16* src = qkv + 2 * E_ + (size_t)(b * S_ + j0 + l) * 3072 + h * 64 + db * 8;
            uint4 d16 = *(const uint4*)src;
            u32 uu[4] = {d16.x, d16.y, d16.z, d16.w};
#pragma unroll
            for (int e = 0; e < 8; e++) {
                u16 raw = (e & 1) ? (u16)(uu[e >> 1] >> 16) : (u16)(uu[e >> 1] & 0xffffu);
                int d = db * 8 + e;
                Vt[((d << 6) + l) ^ ((d & 7) << 3)] = raw;
            }
        }
        __syncthreads();

        // QK^T swapped: s0/s1 = S^T for kv subtiles 0/1 (C: col=q, row=cc(reg)+4hi)
        f32x16 s0 = zf16, s1 = zf16;
        __builtin_amdgcn_s_setprio(1);
#pragma unroll
        for (int g = 0; g < 4; g++) {
            int r0 = q31, r1 = 32 + q31;
            bf16x8 k0 = *(const bf16x8*)&Ks[((r0 << 6) + hi * 8 + 16 * g) ^ ((r0 & 7) << 3)];
            bf16x8 k1 = *(const bf16x8*)&Ks[((r1 << 6) + hi * 8 + 16 * g) ^ ((r1 & 7) << 3)];
            s0 = __builtin_amdgcn_mfma_f32_32x32x16_bf16(k0, qreg[g], s0, 0, 0, 0);
            s1 = __builtin_amdgcn_mfma_f32_32x32x16_bf16(k1, qreg[g], s1, 0, 0, 0);
        }
        __builtin_amdgcn_s_setprio(0);

        // mask + in-lane row max
        float mx = -INFINITY;
        int cb0 = j0 + 4 * hi;
        if (jt == qt) {  // single boundary tile: causal + periodic
#pragma unroll
            for (int r = 0; r < 16; r++) {
                const int cc = (r & 3) + 8 * (r >> 2);
                float v0 = s0[r], v1 = s1[r];
                bool bad0 = (cb0 + cc > rowq) || (r == 15 && hi);
                bool bad1 = (cb0 + 32 + cc > rowq) || (r == 15 && hi);
                v0 = bad0 ? -INFINITY : v0;
                v1 = bad1 ? -INFINITY : v1;
                s0[r] = v0; s1[r] = v1;
                mx = fmaxf(mx, fmaxf(v0, v1));
            }
        } else {  // interior: periodic only (reg 15, hi half)
#pragma unroll
            for (int r = 0; r < 16; r++) {
                float v0 = s0[r], v1 = s1[r];
                if (r == 15) {
                    v0 = hi ? -INFINITY : v0;
                    v1 = hi ? -INFINITY : v1;
                    s0[r] = v0; s1[r] = v1;
                }
                mx = fmaxf(mx, fmaxf(v0, v1));
            }
        }
        mx = fmaxf(mx, __shfl_xor(mx, 32, 64));

        bool dokeep = __all(mx <= mrun + THR);  // false on first tile (mrun=-inf)
        if (!dokeep) {
            float mnew = fmaxf(mrun, mx);
            float sc = __builtin_amdgcn_exp2f((mrun - mnew) * qs);  // 0 on first tile
#pragma unroll
            for (int r = 0; r < 16; r++) { o0[r] *= sc; o1[r] *= sc; }
            lrun *= sc;
            mrun = mnew;
        }
        float mq = mrun * qs;

        // exp2 (scale folded) + partial row sum (4 chains)
        float sa = 0.f, sb = 0.f, sc2 = 0.f, sd = 0.f;
#pragma unroll
        for (int r = 0; r < 16; r++) {
            float p0 = __builtin_amdgcn_exp2f(fmaf(s0[r], qs, -mq));
            float p1 = __builtin_amdgcn_exp2f(fmaf(s1[r], qs, -mq));
            s0[r] = p0; s1[r] = p1;
            if (r & 1) { sb += p0; sd += p1; } else { sa += p0; sc2 += p1; }
        }
        lrun += (sa + sb) + (sc2 + sd);

        // pack P -> bf16 B-operand frags via cvt_pk + permlane32_swap
        bf16x8 pa[4];
#pragma unroll
        for (int g = 0; g < 4; g++) {
            const int bs = (g & 1) * 8;
            u32 wa, wb, wc, wd;
            if (g < 2) {
                wa = cvtpk(s0[bs + 0], s0[bs + 1]);
                wb = cvtpk(s0[bs + 4], s0[bs + 5]);
                wc = cvtpk(s0[bs + 2], s0[bs + 3]);
                wd = cvtpk(s0[bs + 6], s0[bs + 7]);
            } else {
                wa = cvtpk(s1[bs + 0], s1[bs + 1]);
                wb = cvtpk(s1[bs + 4], s1[bs + 5]);
                wc = cvtpk(s1[bs + 2], s1[bs + 3]);
                wd = cvtpk(s1[bs + 6], s1[bs + 7]);
            }
            pswap(wa, wb);
            pswap(wc, wd);
            union { u32 w[4]; bf16x8 f; } u;
            u.w[0] = wa; u.w[1] = wc; u.w[2] = wb; u.w[3] = wd;
            pa[g] = u.f;
        }

        // PV: O^T[d][q] += mfma(A=V^T frag, B=P^T frag)
        __builtin_amdgcn_s_setprio(1);
#pragma unroll
        for (int g = 0; g < 4; g++) {
            int d0 = q31, d1 = 32 + q31;
            bf16x8 v0 = *(const bf16x8*)&Vt[((d0 << 6) + hi * 8 + 16 * g) ^ ((d0 & 7) << 3)];
            bf16x8 v1 = *(const bf16x8*)&Vt[((d1 << 6) + hi * 8 + 16 * g) ^ ((d1 & 7) << 3)];
            o0 = __builtin_amdgcn_mfma_f32_32x32x16_bf16(v0, pa[g], o0, 0, 0, 0);
            o1 = __builtin_amdgcn_mfma_f32_32x32x16_bf16(v1, pa[g], o1, 0, 0, 0);
        }
        __builtin_amdgcn_s_setprio(0);
    }

    // epilogue: finish denominator (partner half), normalize, store
    lrun += __shfl_xor(lrun, 32, 64);
    float inv = 1.0f / lrun;
    u16* orow = aout + (size_t)(b * S_ + rowq) * E_ + h * 64 + 4 * hi;
#pragma unroll
    for (int r = 0; r < 16; r++) {
        const int cc = (r & 3) + 8 * (r >> 2);
        orow[cc] = f2bf(o0[r] * inv);
        orow[32 + cc] = f2bf(o1[r] * inv);
    }
}

extern "C" void kernel_launch(void* const* d_in, const int* in_sizes, int n_in,
                              void* d_out, int out_size, void* d_ws, size_t ws_size,
                              hipStream_t stream) {
    const float* x = (const float*)d_in[0];
    const float* ln1_g = (const float*)d_in[2];
    const float* ln1_b = (const float*)d_in[3];
    const float* ln2_g = (const float*)d_in[4];
    const float* ln2_b = (const float*)d_in[5];
    const float* w_qkv = (const float*)d_in[6];
    const float* b_qkv = (const float*)d_in[7];
    const float* w_o = (const float*)d_in[8];
    const float* b_o = (const float*)d_in[9];
    const float* w_fc1 = (const float*)d_in[10];
    const float* b_fc1 = (const float*)d_in[11];
    const float* w_fc2 = (const float*)d_in[12];
    const float* b_fc2 = (const float*)d_in[13];
    float* out = (float*)d_out;
    char* ws = (char*)d_ws;

    u16* wqkv_bf = (u16*)(ws);                  // 6291456
    u16* wo_bf   = (u16*)(ws + 6291456);        // 2097152
    u16* wfc1_bf = (u16*)(ws + 8388608);        // 8388608
    u16* wfc2_bf = (u16*)(ws + 16777216);       // 8388608
    u16* xn_bf   = (u16*)(ws + 25165824);       // 16777216 (LN1 out; reused as LN2 out)
    u16* qkv_bf  = (u16*)(ws + 41943040);       // 50331648 (reused by ffn1)
    u16* ffn1_bf = (u16*)(ws + 41943040);       // 67108864
    u16* attn_bf = (u16*)(ws + 92274688);       // 16777216
    float* x2    = (float*)(ws + 109051904);    // 33554432
    (void)in_sizes; (void)n_in; (void)out_size; (void)ws_size;

    cvt_kernel<<<3072, 256, 0, stream>>>(w_qkv, wqkv_bf, 786432);
    cvt_kernel<<<1024, 256, 0, stream>>>(w_o, wo_bf, 262144);
    cvt_kernel<<<4096, 256, 0, stream>>>(w_fc1, wfc1_bf, 1048576);
    cvt_kernel<<<4096, 256, 0, stream>>>(w_fc2, wfc2_bf, 1048576);

    ln_kernel<<<M_, 256, 0, stream>>>(x, ln1_g, ln1_b, xn_bf);

    gemm256<0, 256><<<384, 512, 0, stream>>>(xn_bf, wqkv_bf, b_qkv, qkv_bf, nullptr, 3072, 1024);

    attn_kernel<<<2048, 128, 0, stream>>>(qkv_bf, attn_bf);

    gemm256<1, 128><<<256, 512, 0, stream>>>(attn_bf, wo_bf, b_o, x2, x, 1024, 1024);

    ln_kernel<<<M_, 256, 0, stream>>>(x2, ln2_g, ln2_b, xn_bf);

    gemm256<2, 256><<<512, 512, 0, stream>>>(xn_bf, wfc1_bf, b_fc1, ffn1_bf, nullptr, 4096, 1024);

    gemm256<1, 128><<<256, 512, 0, stream>>>(ffn1_bf, wfc2_bf, b_fc2, out, x2, 1024, 4096);
}